// Round 1
// baseline (124.724 us; speedup 1.0000x reference)
//
#include <hip/hip_runtime.h>

// PScan: Y[b,t,c,r,j] = A[b,t,c,r] * Y[b,t-1,c,r,j] + X[b,t,c,r,j]
// 65536 independent scalar recurrences (one per (b,c,r,j)), length L=1024.
// Memory-bound: ~553 MB total traffic -> ~88 us roofline at 6.3 TB/s.

constexpr int B = 4, L = 1024, C = 64, R = 16;
constexpr int CRR = C * R * R;   // 16384  (t-stride of X/Y in elements)
constexpr int CR  = C * R;       // 1024   (t-stride of A in elements)
constexpr int UNROLL = 8;        // 16 outstanding loads per wave per batch

__global__ __launch_bounds__(256)
void pscan_kernel(const float* __restrict__ A,
                  const float* __restrict__ X,
                  float* __restrict__ Y)
{
    const int tid   = blockIdx.x * blockDim.x + threadIdx.x;  // 0..65535
    const int b     = tid >> 14;          // tid / CRR (B*CRR = 65536 threads)
    const int inner = tid & (CRR - 1);    // c*256 + r*16 + j

    const float* Ap = A + (size_t)b * L * CR  + (inner >> 4);  // c*16 + r
    const float* Xp = X + (size_t)b * L * CRR + inner;
    float*       Yp = Y + (size_t)b * L * CRR + inner;

    float y = 0.0f;  // inclusive scan: Y[0] = a0*0 + x0 = x0

    for (int t = 0; t < L; t += UNROLL) {
        float av[UNROLL], xv[UNROLL];
        // Batch all loads first (independent of y) so they issue back-to-back
        // and overlap the dependent FMA chain of the previous batch.
        #pragma unroll
        for (int k = 0; k < UNROLL; ++k) {
            av[k] = Ap[(size_t)k * CR];
            xv[k] = Xp[(size_t)k * CRR];
        }
        #pragma unroll
        for (int k = 0; k < UNROLL; ++k) {
            y = fmaf(av[k], y, xv[k]);
            Yp[(size_t)k * CRR] = y;
        }
        Ap += (size_t)UNROLL * CR;
        Xp += (size_t)UNROLL * CRR;
        Yp += (size_t)UNROLL * CRR;
    }
}

extern "C" void kernel_launch(void* const* d_in, const int* in_sizes, int n_in,
                              void* d_out, int out_size, void* d_ws, size_t ws_size,
                              hipStream_t stream)
{
    const float* A = (const float*)d_in[0];   // [B,L,C,R]
    const float* X = (const float*)d_in[1];   // [B,L,C,R,R]
    float*       Y = (float*)d_out;           // [B,L,C,R,R]

    const int total_threads = B * CRR;        // 65536
    pscan_kernel<<<total_threads / 256, 256, 0, stream>>>(A, X, Y);
}

// Round 2
// 108.998 us; speedup vs baseline: 1.1443x; 1.1443x over previous
//
#include <hip/hip_runtime.h>

// PScan: Y[b,t,c,r,j] = A[b,t,c,r] * Y[b,t-1,c,r,j] + X[b,t,c,r,j]
// 65536 independent scalar recurrences (one per (b,c,r,j)), length L=1024.
// Memory-bound: ~553 MB total traffic -> ~85 us roofline at ~6.5 TB/s.
//
// Parallelism is structurally capped at 65536 threads = 1 wave/SIMD, so
// latency hiding is pure ILP: 16-deep unroll + explicit ping-pong prefetch
// (statically named buffers -- runtime-indexed reg arrays spill to scratch)
// keeps a full batch of loads in flight across every waitcnt.

constexpr int B = 4, L = 1024, C = 64, R = 16;
constexpr int CRR = C * R * R;   // 16384  (t-stride of X/Y in elements)
constexpr int CR  = C * R;       // 1024   (t-stride of A in elements)
constexpr int U   = 16;          // batch depth; 2 batches in flight

__global__ __launch_bounds__(256)
void pscan_kernel(const float* __restrict__ A,
                  const float* __restrict__ X,
                  float* __restrict__ Y)
{
    const int tid   = blockIdx.x * blockDim.x + threadIdx.x;  // 0..65535
    const int b     = tid >> 14;          // tid / CRR
    const int inner = tid & (CRR - 1);    // c*256 + r*16 + j

    const float* Ap = A + (size_t)b * L * CR  + (inner >> 4);  // c*16 + r
    const float* Xp = X + (size_t)b * L * CRR + inner;
    float*       Yp = Y + (size_t)b * L * CRR + inner;

    float a0[U], x0[U], a1[U], x1[U];

    // Prologue: batch 0 into buffer 0.
    #pragma unroll
    for (int k = 0; k < U; ++k) {
        a0[k] = Ap[(size_t)k * CR];
        x0[k] = __builtin_nontemporal_load(Xp + (size_t)k * CRR);
    }

    float y = 0.0f;  // inclusive scan: Y[0] = x0

    for (int t = 0; t < L; t += 2 * U) {
        // Issue loads for batch t+U (always in range: t <= L-2U).
        #pragma unroll
        for (int k = 0; k < U; ++k) {
            a1[k] = Ap[(size_t)(U + k) * CR];
            x1[k] = __builtin_nontemporal_load(Xp + (size_t)(U + k) * CRR);
        }
        // Compute batch t from buffer 0 (waits only on buf0's loads;
        // buf1's 16+ loads remain outstanding).
        #pragma unroll
        for (int k = 0; k < U; ++k) {
            y = fmaf(a0[k], y, x0[k]);
            __builtin_nontemporal_store(y, Yp + (size_t)k * CRR);
        }
        // Issue loads for batch t+2U into buffer 0 (guard last iteration).
        if (t + 2 * U < L) {
            #pragma unroll
            for (int k = 0; k < U; ++k) {
                a0[k] = Ap[(size_t)(2 * U + k) * CR];
                x0[k] = __builtin_nontemporal_load(Xp + (size_t)(2 * U + k) * CRR);
            }
        }
        // Compute batch t+U from buffer 1.
        #pragma unroll
        for (int k = 0; k < U; ++k) {
            y = fmaf(a1[k], y, x1[k]);
            __builtin_nontemporal_store(y, Yp + (size_t)(U + k) * CRR);
        }
        Ap += (size_t)(2 * U) * CR;
        Xp += (size_t)(2 * U) * CRR;
        Yp += (size_t)(2 * U) * CRR;
    }
}

extern "C" void kernel_launch(void* const* d_in, const int* in_sizes, int n_in,
                              void* d_out, int out_size, void* d_ws, size_t ws_size,
                              hipStream_t stream)
{
    const float* A = (const float*)d_in[0];   // [B,L,C,R]
    const float* X = (const float*)d_in[1];   // [B,L,C,R,R]
    float*       Y = (float*)d_out;           // [B,L,C,R,R]

    const int total_threads = B * CRR;        // 65536
    pscan_kernel<<<total_threads / 256, 256, 0, stream>>>(A, X, Y);
}

// Round 3
// 104.338 us; speedup vs baseline: 1.1954x; 1.0447x over previous
//
#include <hip/hip_runtime.h>

// PScan: Y[b,t,c,r,j] = A[b,t,c,r] * Y[b,t-1,c,r,j] + X[b,t,c,r,j]
// 65536 independent scalar recurrences (one per (b,c,r,j)), length L=1024.
// Memory-bound: ~553 MB total traffic -> ~88 us roofline at ~6.3 TB/s mixed.
//
// TLP is capped at 1 wave/SIMD (65536 threads), so latency hiding is pure
// ILP. 4-stage software pipeline: each batch's loads are issued 3 compute
// phases (~450+ cy) before use, vs 1 phase in the 2-buffer version. Steady
// state keeps ~48 loads/wave in flight (vmcnt cap 63). Buffers are
// statically named (runtime-indexed reg arrays would spill to scratch).

constexpr int B = 4, L = 1024, C = 64, R = 16;
constexpr int CRR = C * R * R;   // 16384  (t-stride of X/Y in elements)
constexpr int CR  = C * R;       // 1024   (t-stride of A in elements)
constexpr int U   = 8;           // batch depth; 4 batches in rotation

__global__ __launch_bounds__(256)
void pscan_kernel(const float* __restrict__ A,
                  const float* __restrict__ X,
                  float* __restrict__ Y)
{
    const int tid   = blockIdx.x * blockDim.x + threadIdx.x;  // 0..65535
    const int b     = tid >> 14;          // tid / CRR
    const int inner = tid & (CRR - 1);    // c*256 + r*16 + j

    const float* Ap = A + (size_t)b * L * CR  + (inner >> 4);  // c*16 + r
    const float* Xp = X + (size_t)b * L * CRR + inner;
    float*       Yp = Y + (size_t)b * L * CRR + inner;

    float a0[U], x0[U], a1[U], x1[U], a2[U], x2[U], a3[U], x3[U];

    #define LOAD(av, xv, t0)                                               \
        _Pragma("unroll")                                                  \
        for (int k = 0; k < U; ++k) {                                      \
            av[k] = Ap[(size_t)((t0) + k) * CR];                           \
            xv[k] = __builtin_nontemporal_load(Xp + (size_t)((t0) + k) * CRR); \
        }

    #define COMPUTE(av, xv, t0)                                            \
        _Pragma("unroll")                                                  \
        for (int k = 0; k < U; ++k) {                                      \
            y = fmaf(av[k], y, xv[k]);                                     \
            __builtin_nontemporal_store(y, Yp + (size_t)((t0) + k) * CRR); \
        }

    // Prologue: fill 3 of the 4 stages.
    LOAD(a0, x0, 0)
    LOAD(a1, x1, U)
    LOAD(a2, x2, 2 * U)

    float y = 0.0f;  // inclusive scan: Y[0] = x0

    for (int t = 0; t < L; t += 4 * U) {
        LOAD(a3, x3, t + 3 * U)
        COMPUTE(a0, x0, t)
        if (t + 4 * U < L) { LOAD(a0, x0, t + 4 * U) }
        COMPUTE(a1, x1, t + U)
        if (t + 5 * U < L) { LOAD(a1, x1, t + 5 * U) }
        COMPUTE(a2, x2, t + 2 * U)
        if (t + 6 * U < L) { LOAD(a2, x2, t + 6 * U) }
        COMPUTE(a3, x3, t + 3 * U)
    }

    #undef LOAD
    #undef COMPUTE
}

extern "C" void kernel_launch(void* const* d_in, const int* in_sizes, int n_in,
                              void* d_out, int out_size, void* d_ws, size_t ws_size,
                              hipStream_t stream)
{
    const float* A = (const float*)d_in[0];   // [B,L,C,R]
    const float* X = (const float*)d_in[1];   // [B,L,C,R,R]
    float*       Y = (float*)d_out;           // [B,L,C,R,R]

    const int total_threads = B * CRR;        // 65536
    pscan_kernel<<<total_threads / 256, 256, 0, stream>>>(A, X, Y);
}